// Round 3
// baseline (472.498 us; speedup 1.0000x reference)
//
#include <hip/hip_runtime.h>

#define Bb 8
#define Cc 64
#define Tt 16
#define Hh 56
#define Ww 56
#define COUT 128
#define HW (Hh*Ww)            // 3136
#define THW (Tt*HW)           // 50176
#define NPG ((double)(32*THW))

// ---------------------------------------------------------------------------
// K1: fused depthwise spatial 3x3 + temporal 3-tap, ring-buffered in LDS.
// One block per (b, c, t-quad). Loads up to 6 raw planes, emits 4 z planes.
// ---------------------------------------------------------------------------
__global__ __launch_bounds__(256) void k1_dwconv(
    const float* __restrict__ x,  const float* __restrict__ sw,
    const float* __restrict__ sb, const float* __restrict__ tw,
    const float* __restrict__ tb, float* __restrict__ z)
{
  __shared__ float raw[HW];          // 12.25 KB
  __shared__ float ring[3][HW];      // 36.75 KB

  const int tid = threadIdx.x;
  const int ts = blockIdx.x & 3;
  const int c  = (blockIdx.x >> 2) & 63;
  const int b  =  blockIdx.x >> 8;
  const int t0 = ts * 4;

  float s9[9];
#pragma unroll
  for (int k = 0; k < 9; ++k) s9[k] = sw[c * 9 + k];
  float t3a[3];
#pragma unroll
  for (int k = 0; k < 3; ++k) t3a[k] = tw[c * 3 + k];
  const float sbc = sb[c], tbc = tb[c];

  const float* xbase = x + (size_t)(b * Cc + c) * THW;
  float*       zbase = z + (size_t)(b * Cc + c) * THW;

  for (int tt = t0 - 1; tt <= t0 + 4; ++tt) {
    // ---- load raw plane tt ----
    if (tt >= 0 && tt < Tt) {
      const float* xp = xbase + tt * HW;
      for (int f = tid; f < HW / 4; f += 256)
        *(float4*)&raw[f * 4] = *(const float4*)(xp + f * 4);
    }
    __syncthreads();

    // ---- spatial 3x3: raw -> ring[tt%3] ----
    if (tt >= 0 && tt < Tt) {
      float* rg = ring[tt % 3];
      for (int q = tid; q < HW / 4; q += 256) {
        int h  = q / 14;
        int w0 = (q - h * 14) * 4;
        float4 sacc = make_float4(sbc, sbc, sbc, sbc);
#pragma unroll
        for (int dh = -1; dh <= 1; ++dh) {
          int hh = h + dh;
          if (hh < 0 || hh > Hh - 1) continue;
          const float* rr = &raw[hh * Ww];
          float4 mv = *(const float4*)(rr + w0);
          float lf = (w0 > 0)      ? rr[w0 - 1] : 0.0f;
          float rt = (w0 < Ww - 4) ? rr[w0 + 4] : 0.0f;
          float k0 = s9[(dh + 1) * 3 + 0];
          float k1 = s9[(dh + 1) * 3 + 1];
          float k2 = s9[(dh + 1) * 3 + 2];
          sacc.x = fmaf(k0, lf,   fmaf(k1, mv.x, fmaf(k2, mv.y, sacc.x)));
          sacc.y = fmaf(k0, mv.x, fmaf(k1, mv.y, fmaf(k2, mv.z, sacc.y)));
          sacc.z = fmaf(k0, mv.y, fmaf(k1, mv.z, fmaf(k2, mv.w, sacc.z)));
          sacc.w = fmaf(k0, mv.z, fmaf(k1, mv.w, fmaf(k2, rt,   sacc.w)));
        }
        *(float4*)&rg[q * 4] = sacc;
      }
    }
    __syncthreads();

    // ---- temporal emit t_out = tt-1 (ring holds tt-2, tt-1, tt) ----
    int t_out = tt - 1;
    if (t_out >= t0 && t_out <= t0 + 3) {
      float* zp = zbase + t_out * HW;
      for (int q = tid; q < HW / 4; q += 256) {
        float4 a = make_float4(tbc, tbc, tbc, tbc);
#pragma unroll
        for (int dt = -1; dt <= 1; ++dt) {
          int ti = t_out + dt;
          if (ti < 0 || ti > Tt - 1) continue;
          float tk = t3a[dt + 1];
          float4 v = *(const float4*)&ring[ti % 3][q * 4];
          a.x = fmaf(tk, v.x, a.x);
          a.y = fmaf(tk, v.y, a.y);
          a.z = fmaf(tk, v.z, a.z);
          a.w = fmaf(tk, v.w, a.w);
        }
        *(float4*)(zp + q * 4) = a;
      }
    }
    __syncthreads();
  }
}

// ---------------------------------------------------------------------------
// GEMM tile: 128 pos x 128 out per block, 8x8 per thread in two float4
// halves at stride 64 (bank-conflict-free LDS reads).
// ---------------------------------------------------------------------------
#define GEMM_STAGE_AND_ACC()                                                   \
  __shared__ float zt[64 * 128];                                               \
  __shared__ float wt[64 * 128];                                               \
  const int tid = threadIdx.x;                                                 \
  const int b  = blockIdx.x / 392;                                             \
  const int p0 = (blockIdx.x - b * 392) * 128;                                 \
  {                                                                            \
    const float* zb = z + (size_t)b * Cc * THW + p0;                           \
    for (int f = tid; f < 2048; f += 256) {                                    \
      int k  = f >> 5;                                                         \
      int po = (f & 31) << 2;                                                  \
      *(float4*)&zt[k * 128 + po] = *(const float4*)(zb + (size_t)k * THW + po);\
    }                                                                          \
  }                                                                            \
  if (tid < 128) {                                                             \
    const float* wr = pw + tid * 64;                                           \
    _Pragma("unroll")                                                          \
    for (int k = 0; k < 64; k += 4) {                                          \
      float4 v = *(const float4*)(wr + k);                                     \
      wt[(k + 0) * 128 + tid] = v.x;                                           \
      wt[(k + 1) * 128 + tid] = v.y;                                           \
      wt[(k + 2) * 128 + tid] = v.z;                                           \
      wt[(k + 3) * 128 + tid] = v.w;                                           \
    }                                                                          \
  }                                                                            \
  __syncthreads();                                                             \
  const int tx = tid & 15, ty = tid >> 4;                                      \
  float acc[8][8];                                                             \
  _Pragma("unroll")                                                            \
  for (int oi = 0; oi < 8; ++oi)                                               \
    _Pragma("unroll")                                                          \
    for (int pj = 0; pj < 8; ++pj) acc[oi][pj] = 0.0f;                         \
  {                                                                            \
    const float* ztp = &zt[tx * 4];                                            \
    const float* wtp = &wt[ty * 4];                                            \
    _Pragma("unroll 4")                                                        \
    for (int k = 0; k < 64; ++k) {                                             \
      float4 z0 = *(const float4*)(ztp + k * 128);                             \
      float4 z1 = *(const float4*)(ztp + k * 128 + 64);                        \
      float4 w0 = *(const float4*)(wtp + k * 128);                             \
      float4 w1 = *(const float4*)(wtp + k * 128 + 64);                        \
      float zr[8]   = {z0.x, z0.y, z0.z, z0.w, z1.x, z1.y, z1.z, z1.w};        \
      float wreg[8] = {w0.x, w0.y, w0.z, w0.w, w1.x, w1.y, w1.z, w1.w};        \
      _Pragma("unroll")                                                        \
      for (int oi = 0; oi < 8; ++oi)                                           \
        _Pragma("unroll")                                                      \
        for (int pj = 0; pj < 8; ++pj)                                         \
          acc[oi][pj] = fmaf(wreg[oi], zr[pj], acc[oi][pj]);                   \
    }                                                                          \
  }                                                                            \
  const int olo = ty * 4, ohi = 64 + ty * 4;

// K2: GEMM -> per-(b,group) sum / sumsq (double atomics).
__global__ __launch_bounds__(256) void k2_stats(
    const float* __restrict__ z, const float* __restrict__ pw,
    const float* __restrict__ pb, double* __restrict__ stats)
{
  GEMM_STAGE_AND_ACC();

  float s1lo = 0.0f, s2lo = 0.0f, s1hi = 0.0f, s2hi = 0.0f;
#pragma unroll
  for (int oi = 0; oi < 4; ++oi) {
    float blo = pb[olo + oi], bhi = pb[ohi + oi];
#pragma unroll
    for (int pj = 0; pj < 8; ++pj) {
      float dl = acc[oi][pj] + blo;
      float dh = acc[oi + 4][pj] + bhi;
      s1lo += dl; s2lo = fmaf(dl, dl, s2lo);
      s1hi += dh; s2hi = fmaf(dh, dh, s2hi);
    }
  }
#pragma unroll
  for (int off = 32; off; off >>= 1) {
    s1lo += __shfl_xor(s1lo, off);
    s2lo += __shfl_xor(s2lo, off);
    s1hi += __shfl_xor(s1hi, off);
    s2hi += __shfl_xor(s2hi, off);
  }
  if ((tid & 63) == 0) {
    int glo = ty >> 3;          // wave-uniform (ty>>3 same for all 4 ty in wave)
    int ghi = 2 + (ty >> 3);
    atomicAdd(&stats[(b * 4 + glo) * 2 + 0], (double)s1lo);
    atomicAdd(&stats[(b * 4 + glo) * 2 + 1], (double)s2lo);
    atomicAdd(&stats[(b * 4 + ghi) * 2 + 0], (double)s1hi);
    atomicAdd(&stats[(b * 4 + ghi) * 2 + 1], (double)s2hi);
  }
}

// K3: GEMM recompute -> GroupNorm + affine + ReLU -> out.
__global__ __launch_bounds__(256) void k3_norm(
    const float* __restrict__ z, const float* __restrict__ pw,
    const float* __restrict__ pb, const double* __restrict__ stats,
    const float* __restrict__ gnw, const float* __restrict__ gnb,
    float* __restrict__ out)
{
  GEMM_STAGE_AND_ACC();

  const int glo = ty >> 3, ghi = 2 + (ty >> 3);
  double s1l = stats[(b * 4 + glo) * 2 + 0];
  double s2l = stats[(b * 4 + glo) * 2 + 1];
  double s1h = stats[(b * 4 + ghi) * 2 + 0];
  double s2h = stats[(b * 4 + ghi) * 2 + 1];
  double mld = s1l / NPG, vld = s2l / NPG - mld * mld;
  double mhd = s1h / NPG, vhd = s2h / NPG - mhd * mhd;
  float mlo = (float)mld, invlo = rsqrtf((float)vld + 1e-5f);
  float mhi = (float)mhd, invhi = rsqrtf((float)vhd + 1e-5f);

  float* ob = out + (size_t)b * COUT * THW + p0;
#pragma unroll
  for (int oi = 0; oi < 8; ++oi) {
    int o    = (oi < 4) ? (olo + oi) : (ohi + oi - 4);
    float m  = (oi < 4) ? mlo : mhi;
    float iv = (oi < 4) ? invlo : invhi;
    float A = iv * gnw[o];
    float B = fmaf(pb[o] - m, A, gnb[o]);
    float v0 = fmaf(acc[oi][0], A, B); v0 = v0 > 0.0f ? v0 : 0.0f;
    float v1 = fmaf(acc[oi][1], A, B); v1 = v1 > 0.0f ? v1 : 0.0f;
    float v2 = fmaf(acc[oi][2], A, B); v2 = v2 > 0.0f ? v2 : 0.0f;
    float v3 = fmaf(acc[oi][3], A, B); v3 = v3 > 0.0f ? v3 : 0.0f;
    float v4 = fmaf(acc[oi][4], A, B); v4 = v4 > 0.0f ? v4 : 0.0f;
    float v5 = fmaf(acc[oi][5], A, B); v5 = v5 > 0.0f ? v5 : 0.0f;
    float v6 = fmaf(acc[oi][6], A, B); v6 = v6 > 0.0f ? v6 : 0.0f;
    float v7 = fmaf(acc[oi][7], A, B); v7 = v7 > 0.0f ? v7 : 0.0f;
    float* orow = ob + (size_t)o * THW;
    *(float4*)(orow + tx * 4)      = make_float4(v0, v1, v2, v3);
    *(float4*)(orow + 64 + tx * 4) = make_float4(v4, v5, v6, v7);
  }
}

// ---------------------------------------------------------------------------
extern "C" void kernel_launch(void* const* d_in, const int* in_sizes, int n_in,
                              void* d_out, int out_size, void* d_ws, size_t ws_size,
                              hipStream_t stream)
{
  const float* x   = (const float*)d_in[0];
  const float* sw  = (const float*)d_in[1];
  const float* sb  = (const float*)d_in[2];
  const float* tw  = (const float*)d_in[3];
  const float* tb  = (const float*)d_in[4];
  const float* pw  = (const float*)d_in[5];
  const float* pb  = (const float*)d_in[6];
  const float* gnw = (const float*)d_in[7];
  const float* gnb = (const float*)d_in[8];
  float* out = (float*)d_out;

  double* stats = (double*)d_ws;                     // 64 doubles = 512 B
  float*  z     = (float*)((char*)d_ws + 512);       // 25,690,112 floats

  hipMemsetAsync(stats, 0, 64 * sizeof(double), stream);

  k1_dwconv<<<Bb * Cc * 4, 256, 0, stream>>>(x, sw, sb, tw, tb, z); // 2048 blocks
  k2_stats<<<Bb * 392, 256, 0, stream>>>(z, pw, pb, stats);         // 3136 blocks
  k3_norm <<<Bb * 392, 256, 0, stream>>>(z, pw, pb, stats, gnw, gnb, out);
}

// Round 4
// 289.141 us; speedup vs baseline: 1.6341x; 1.6341x over previous
//
#include <hip/hip_runtime.h>
#include <hip/hip_bf16.h>

#define Bb 8
#define Cc 64
#define Tt 16
#define Hh 56
#define Ww 56
#define COUT 128
#define HW (Hh*Ww)            // 3136
#define THW (Tt*HW)           // 50176
#define NPG ((double)(32*THW))

typedef __attribute__((ext_vector_type(8))) short short8v;   // 8 bf16
typedef __attribute__((ext_vector_type(4))) float f32x4;

__device__ __forceinline__ unsigned short f2bf(float x) {
  __hip_bfloat16 h = __float2bfloat16(x);
  return *reinterpret_cast<unsigned short*>(&h);
}

// ---------------------------------------------------------------------------
// K1: fused depthwise spatial 3x3 + temporal 3-tap, ring-buffered in LDS.
// One block per (b, c, t-quad). Emits z as bf16 in [b][c/2][pos][2] layout
// (channel-pair interleave) so the GEMM gets k-contiguous bf16 pairs.
// ---------------------------------------------------------------------------
__global__ __launch_bounds__(256) void k1_dwconv(
    const float* __restrict__ x,  const float* __restrict__ sw,
    const float* __restrict__ sb, const float* __restrict__ tw,
    const float* __restrict__ tb, unsigned short* __restrict__ zs)
{
  __shared__ float raw[HW];          // 12.25 KB
  __shared__ float ring[3][HW];      // 36.75 KB

  const int tid = threadIdx.x;
  const int ts = blockIdx.x & 3;
  const int c  = (blockIdx.x >> 2) & 63;
  const int b  =  blockIdx.x >> 8;
  const int t0 = ts * 4;

  float s9[9];
#pragma unroll
  for (int k = 0; k < 9; ++k) s9[k] = sw[c * 9 + k];
  float t3a[3];
#pragma unroll
  for (int k = 0; k < 3; ++k) t3a[k] = tw[c * 3 + k];
  const float sbc = sb[c], tbc = tb[c];

  const float* xbase = x + (size_t)(b * Cc + c) * THW;

  for (int tt = t0 - 1; tt <= t0 + 4; ++tt) {
    if (tt >= 0 && tt < Tt) {
      const float* xp = xbase + tt * HW;
      for (int f = tid; f < HW / 4; f += 256)
        *(float4*)&raw[f * 4] = *(const float4*)(xp + f * 4);
    }
    __syncthreads();

    if (tt >= 0 && tt < Tt) {
      float* rg = ring[tt % 3];
      for (int q = tid; q < HW / 4; q += 256) {
        int h  = q / 14;
        int w0 = (q - h * 14) * 4;
        float4 sacc = make_float4(sbc, sbc, sbc, sbc);
#pragma unroll
        for (int dh = -1; dh <= 1; ++dh) {
          int hh = h + dh;
          if (hh < 0 || hh > Hh - 1) continue;
          const float* rr = &raw[hh * Ww];
          float4 mv = *(const float4*)(rr + w0);
          float lf = (w0 > 0)      ? rr[w0 - 1] : 0.0f;
          float rt = (w0 < Ww - 4) ? rr[w0 + 4] : 0.0f;
          float k0 = s9[(dh + 1) * 3 + 0];
          float k1 = s9[(dh + 1) * 3 + 1];
          float k2 = s9[(dh + 1) * 3 + 2];
          sacc.x = fmaf(k0, lf,   fmaf(k1, mv.x, fmaf(k2, mv.y, sacc.x)));
          sacc.y = fmaf(k0, mv.x, fmaf(k1, mv.y, fmaf(k2, mv.z, sacc.y)));
          sacc.z = fmaf(k0, mv.y, fmaf(k1, mv.z, fmaf(k2, mv.w, sacc.z)));
          sacc.w = fmaf(k0, mv.z, fmaf(k1, mv.w, fmaf(k2, rt,   sacc.w)));
        }
        *(float4*)&rg[q * 4] = sacc;
      }
    }
    __syncthreads();

    int t_out = tt - 1;
    if (t_out >= t0 && t_out <= t0 + 3) {
      unsigned short* zp = zs +
          ((size_t)(b * 32 + (c >> 1)) * THW + (size_t)t_out * HW) * 2 + (c & 1);
      for (int q = tid; q < HW / 4; q += 256) {
        float4 a = make_float4(tbc, tbc, tbc, tbc);
#pragma unroll
        for (int dt = -1; dt <= 1; ++dt) {
          int ti = t_out + dt;
          if (ti < 0 || ti > Tt - 1) continue;
          float tk = t3a[dt + 1];
          float4 v = *(const float4*)&ring[ti % 3][q * 4];
          a.x = fmaf(tk, v.x, a.x);
          a.y = fmaf(tk, v.y, a.y);
          a.z = fmaf(tk, v.z, a.z);
          a.w = fmaf(tk, v.w, a.w);
        }
        int p4 = q * 4;
        zp[(size_t)(p4 + 0) * 2] = f2bf(a.x);
        zp[(size_t)(p4 + 1) * 2] = f2bf(a.y);
        zp[(size_t)(p4 + 2) * 2] = f2bf(a.z);
        zp[(size_t)(p4 + 3) * 2] = f2bf(a.w);
      }
    }
    __syncthreads();
  }
}

// ---------------------------------------------------------------------------
// Shared MFMA GEMM tile: 128 pos x 128 out per block, 4 waves, wave w owns
// out rows [w*32, w*32+32) == GroupNorm group w.
// zq: z as uint pairs [b*32+c2][THW]; LDS zt [32 c2][128 pos] dwords, +4 pad.
// acc[ot][pt][r]: o = w*32 + ot*16 + (lane>>4)*4 + r, pos = p0 + pt*16 + (lane&15).
// ---------------------------------------------------------------------------
__device__ __forceinline__ void gemm_tile(
    const unsigned int* __restrict__ zq, const float* __restrict__ pw,
    int b, int p0, int tid, f32x4 acc[2][8])
{
  __shared__ unsigned int zt[32 * 132];   // 16.9 KB

  {
    const unsigned int* zb = zq + (size_t)(b * 32) * THW + p0;
#pragma unroll
    for (int i = 0; i < 4; ++i) {
      int f = tid + i * 256;
      int c2 = f >> 5, po = (f & 31) << 2;
      *(uint4*)&zt[c2 * 132 + po] = *(const uint4*)(zb + (size_t)c2 * THW + po);
    }
  }

  const int lr = tid & 15, lg = (tid >> 4) & 3, wv = tid >> 6;
  const int obase = wv * 32;

  short8v afrag[2][2];
#pragma unroll
  for (int ot = 0; ot < 2; ++ot)
#pragma unroll
    for (int kt = 0; kt < 2; ++kt) {
      int o  = obase + ot * 16 + lr;
      int c0 = kt * 32 + lg * 8;
      float4 wa = *(const float4*)(pw + o * 64 + c0);
      float4 wb = *(const float4*)(pw + o * 64 + c0 + 4);
      short8v f;
      f[0] = (short)f2bf(wa.x); f[1] = (short)f2bf(wa.y);
      f[2] = (short)f2bf(wa.z); f[3] = (short)f2bf(wa.w);
      f[4] = (short)f2bf(wb.x); f[5] = (short)f2bf(wb.y);
      f[6] = (short)f2bf(wb.z); f[7] = (short)f2bf(wb.w);
      afrag[ot][kt] = f;
    }

#pragma unroll
  for (int ot = 0; ot < 2; ++ot)
#pragma unroll
    for (int pt = 0; pt < 8; ++pt) {
      acc[ot][pt][0] = 0.0f; acc[ot][pt][1] = 0.0f;
      acc[ot][pt][2] = 0.0f; acc[ot][pt][3] = 0.0f;
    }

  __syncthreads();

#pragma unroll
  for (int kt = 0; kt < 2; ++kt) {
    const int c2b = kt * 16 + lg * 4;
#pragma unroll
    for (int pt = 0; pt < 8; ++pt) {
      const unsigned int* zp2 = &zt[c2b * 132 + pt * 16 + lr];
      union { unsigned int u[4]; short8v s; } bfu;
      bfu.u[0] = zp2[0];
      bfu.u[1] = zp2[132];
      bfu.u[2] = zp2[264];
      bfu.u[3] = zp2[396];
      acc[0][pt] = __builtin_amdgcn_mfma_f32_16x16x32_bf16(
          afrag[0][kt], bfu.s, acc[0][pt], 0, 0, 0);
      acc[1][pt] = __builtin_amdgcn_mfma_f32_16x16x32_bf16(
          afrag[1][kt], bfu.s, acc[1][pt], 0, 0, 0);
    }
  }
}

// K2: MFMA GEMM -> per-(b,group) sum / sumsq (double atomics).
__global__ __launch_bounds__(256) void k2_stats(
    const unsigned int* __restrict__ zq, const float* __restrict__ pw,
    const float* __restrict__ pb, double* __restrict__ stats)
{
  const int tid = threadIdx.x;
  const int b  = blockIdx.x / 392;
  const int p0 = (blockIdx.x - b * 392) * 128;

  f32x4 acc[2][8];
  gemm_tile(zq, pw, b, p0, tid, acc);

  const int lg = (tid >> 4) & 3, wv = tid >> 6, obase = wv * 32;

  float pbv[2][4];
#pragma unroll
  for (int ot = 0; ot < 2; ++ot)
#pragma unroll
    for (int r = 0; r < 4; ++r)
      pbv[ot][r] = pb[obase + ot * 16 + lg * 4 + r];

  float s1 = 0.0f, s2 = 0.0f;
#pragma unroll
  for (int ot = 0; ot < 2; ++ot)
#pragma unroll
    for (int pt = 0; pt < 8; ++pt)
#pragma unroll
      for (int r = 0; r < 4; ++r) {
        float d = acc[ot][pt][r] + pbv[ot][r];
        s1 += d;
        s2 = fmaf(d, d, s2);
      }

#pragma unroll
  for (int off = 32; off; off >>= 1) {
    s1 += __shfl_xor(s1, off);
    s2 += __shfl_xor(s2, off);
  }
  if ((tid & 63) == 0) {
    atomicAdd(&stats[(b * 4 + wv) * 2 + 0], (double)s1);
    atomicAdd(&stats[(b * 4 + wv) * 2 + 1], (double)s2);
  }
}

// K3: MFMA GEMM recompute -> GroupNorm + affine + ReLU -> out.
__global__ __launch_bounds__(256) void k3_norm(
    const unsigned int* __restrict__ zq, const float* __restrict__ pw,
    const float* __restrict__ pb, const double* __restrict__ stats,
    const float* __restrict__ gnw, const float* __restrict__ gnb,
    float* __restrict__ out)
{
  const int tid = threadIdx.x;
  const int b  = blockIdx.x / 392;
  const int p0 = (blockIdx.x - b * 392) * 128;

  f32x4 acc[2][8];
  gemm_tile(zq, pw, b, p0, tid, acc);

  const int lr = tid & 15, lg = (tid >> 4) & 3, wv = tid >> 6, obase = wv * 32;

  double s1 = stats[(b * 4 + wv) * 2 + 0];
  double s2 = stats[(b * 4 + wv) * 2 + 1];
  double md = s1 / NPG;
  double vd = s2 / NPG - md * md;
  float m   = (float)md;
  float inv = rsqrtf((float)vd + 1e-5f);

#pragma unroll
  for (int ot = 0; ot < 2; ++ot)
#pragma unroll
    for (int r = 0; r < 4; ++r) {
      int o = obase + ot * 16 + lg * 4 + r;
      float A  = inv * gnw[o];
      float Bc = fmaf(pb[o] - m, A, gnb[o]);
      float* orow = out + (size_t)(b * COUT + o) * THW + p0 + lr;
#pragma unroll
      for (int pt = 0; pt < 8; ++pt) {
        float v = fmaf(acc[ot][pt][r], A, Bc);
        orow[pt * 16] = v > 0.0f ? v : 0.0f;
      }
    }
}

// ---------------------------------------------------------------------------
extern "C" void kernel_launch(void* const* d_in, const int* in_sizes, int n_in,
                              void* d_out, int out_size, void* d_ws, size_t ws_size,
                              hipStream_t stream)
{
  const float* x   = (const float*)d_in[0];
  const float* sw  = (const float*)d_in[1];
  const float* sb  = (const float*)d_in[2];
  const float* tw  = (const float*)d_in[3];
  const float* tb  = (const float*)d_in[4];
  const float* pw  = (const float*)d_in[5];
  const float* pb  = (const float*)d_in[6];
  const float* gnw = (const float*)d_in[7];
  const float* gnb = (const float*)d_in[8];
  float* out = (float*)d_out;

  double* stats          = (double*)d_ws;                       // 64 doubles
  unsigned short* zs     = (unsigned short*)((char*)d_ws + 512);
  const unsigned int* zq = (const unsigned int*)zs;             // pair view

  hipMemsetAsync(stats, 0, 64 * sizeof(double), stream);

  k1_dwconv<<<Bb * Cc * 4, 256, 0, stream>>>(x, sw, sb, tw, tb, zs); // 2048
  k2_stats<<<Bb * 392, 256, 0, stream>>>(zq, pw, pb, stats);         // 3136
  k3_norm <<<Bb * 392, 256, 0, stream>>>(zq, pw, pb, stats, gnw, gnb, out);
}

// Round 5
// 155.661 us; speedup vs baseline: 3.0354x; 1.8575x over previous
//
#include <hip/hip_runtime.h>
#include <hip/hip_bf16.h>

#define Bb 8
#define Cc 64
#define Tt 16
#define Hh 56
#define Ww 56
#define COUT 128
#define HW (Hh*Ww)            // 3136
#define THW (Tt*HW)           // 50176
#define NPG ((double)(32*THW))

typedef __attribute__((ext_vector_type(8))) short short8v;   // 8 bf16
typedef __attribute__((ext_vector_type(4))) float f32x4;

__device__ __forceinline__ unsigned short f2bf(float x) {
  __hip_bfloat16 h = __float2bfloat16(x);
  return *reinterpret_cast<unsigned short*>(&h);
}
__device__ __forceinline__ float blo(unsigned int u) {
  return __uint_as_float(u << 16);
}
__device__ __forceinline__ float bhi(unsigned int u) {
  return __uint_as_float(u & 0xFFFF0000u);
}
__device__ __forceinline__ unsigned int pack2(float a, float b) {
  return (unsigned int)f2bf(a) | ((unsigned int)f2bf(b) << 16);
}

// ---------------------------------------------------------------------------
// K1: fused depthwise spatial 3x3 + temporal 3-tap. One block per
// (b, channel-PAIR, t-quad). raw & ring planes live in LDS as packed bf16
// pairs (lo = even channel, hi = odd channel) -> z written as full uint4.
// ---------------------------------------------------------------------------
__global__ __launch_bounds__(256) void k1_dwconv(
    const float* __restrict__ x,  const float* __restrict__ sw,
    const float* __restrict__ sb, const float* __restrict__ tw,
    const float* __restrict__ tb, unsigned int* __restrict__ zq)
{
  __shared__ unsigned int raw[HW];        // 12.25 KB (bf16 pair)
  __shared__ unsigned int ring[3][HW];    // 36.75 KB

  const int tid = threadIdx.x;
  const int tq = blockIdx.x & 3;
  const int c2 = (blockIdx.x >> 2) & 31;
  const int b  =  blockIdx.x >> 7;
  const int t0 = tq * 4;
  const int ca = c2 * 2, cb = ca + 1;

  float s9a[9], s9b[9];
#pragma unroll
  for (int k = 0; k < 9; ++k) { s9a[k] = sw[ca * 9 + k]; s9b[k] = sw[cb * 9 + k]; }
  float ta3[3], tb3[3];
#pragma unroll
  for (int k = 0; k < 3; ++k) { ta3[k] = tw[ca * 3 + k]; tb3[k] = tw[cb * 3 + k]; }
  const float sba = sb[ca], sbb = sb[cb];
  const float tba = tb[ca], tbb = tb[cb];

  const float* xa = x + (size_t)(b * Cc + ca) * THW;
  const float* xb = x + (size_t)(b * Cc + cb) * THW;
  unsigned int* zbase = zq + (size_t)(b * 32 + c2) * THW;

  for (int tt = t0 - 1; tt <= t0 + 4; ++tt) {
    // ---- stage raw plane tt as bf16 pairs ----
    if (tt >= 0 && tt < Tt) {
      const float* xpa = xa + tt * HW;
      const float* xpb = xb + tt * HW;
      for (int f = tid; f < HW / 4; f += 256) {
        float4 va = *(const float4*)(xpa + f * 4);
        float4 vb = *(const float4*)(xpb + f * 4);
        uint4 pk;
        pk.x = pack2(va.x, vb.x);
        pk.y = pack2(va.y, vb.y);
        pk.z = pack2(va.z, vb.z);
        pk.w = pack2(va.w, vb.w);
        *(uint4*)&raw[f * 4] = pk;
      }
    }
    __syncthreads();

    // ---- spatial 3x3 conv on both channels: raw -> ring[tt%3] ----
    if (tt >= 0 && tt < Tt) {
      unsigned int* rg = ring[tt % 3];
      for (int q = tid; q < HW / 4; q += 256) {
        int h  = q / 14;
        int w0 = (q - h * 14) * 4;
        float sa0 = sba, sa1 = sba, sa2 = sba, sa3 = sba;
        float sb0 = sbb, sb1 = sbb, sb2 = sbb, sb3 = sbb;
#pragma unroll
        for (int dh = -1; dh <= 1; ++dh) {
          int hh = h + dh;
          if (hh < 0 || hh > Hh - 1) continue;
          const unsigned int* rr = &raw[hh * Ww + w0];
          uint4 mv = *(const uint4*)rr;
          unsigned int lf = (w0 > 0)      ? rr[-1] : 0u;
          unsigned int rt = (w0 < Ww - 4) ? rr[4]  : 0u;
          float am1 = blo(lf),  a0 = blo(mv.x), a1 = blo(mv.y);
          float a2  = blo(mv.z), a3 = blo(mv.w), a4 = blo(rt);
          float bm1 = bhi(lf),  b0 = bhi(mv.x), b1 = bhi(mv.y);
          float b2  = bhi(mv.z), b3 = bhi(mv.w), b4 = bhi(rt);
          float k0a = s9a[(dh + 1) * 3 + 0], k1a = s9a[(dh + 1) * 3 + 1], k2a = s9a[(dh + 1) * 3 + 2];
          float k0b = s9b[(dh + 1) * 3 + 0], k1b = s9b[(dh + 1) * 3 + 1], k2b = s9b[(dh + 1) * 3 + 2];
          sa0 = fmaf(k0a, am1, fmaf(k1a, a0, fmaf(k2a, a1, sa0)));
          sa1 = fmaf(k0a, a0,  fmaf(k1a, a1, fmaf(k2a, a2, sa1)));
          sa2 = fmaf(k0a, a1,  fmaf(k1a, a2, fmaf(k2a, a3, sa2)));
          sa3 = fmaf(k0a, a2,  fmaf(k1a, a3, fmaf(k2a, a4, sa3)));
          sb0 = fmaf(k0b, bm1, fmaf(k1b, b0, fmaf(k2b, b1, sb0)));
          sb1 = fmaf(k0b, b0,  fmaf(k1b, b1, fmaf(k2b, b2, sb1)));
          sb2 = fmaf(k0b, b1,  fmaf(k1b, b2, fmaf(k2b, b3, sb2)));
          sb3 = fmaf(k0b, b2,  fmaf(k1b, b3, fmaf(k2b, b4, sb3)));
        }
        uint4 pk;
        pk.x = pack2(sa0, sb0);
        pk.y = pack2(sa1, sb1);
        pk.z = pack2(sa2, sb2);
        pk.w = pack2(sa3, sb3);
        *(uint4*)&rg[q * 4] = pk;
      }
    }
    __syncthreads();

    // ---- temporal emit t_out = tt-1 -> global z (full dwords) ----
    int t_out = tt - 1;
    if (t_out >= t0 && t_out <= t0 + 3) {
      unsigned int* zp = zbase + (size_t)t_out * HW;
      for (int q = tid; q < HW / 4; q += 256) {
        float aa0 = tba, aa1 = tba, aa2 = tba, aa3 = tba;
        float bb0 = tbb, bb1 = tbb, bb2 = tbb, bb3 = tbb;
#pragma unroll
        for (int dt = -1; dt <= 1; ++dt) {
          int ti = t_out + dt;
          if (ti < 0 || ti > Tt - 1) continue;
          float tka = ta3[dt + 1], tkb = tb3[dt + 1];
          uint4 v = *(const uint4*)&ring[ti % 3][q * 4];
          aa0 = fmaf(tka, blo(v.x), aa0);  bb0 = fmaf(tkb, bhi(v.x), bb0);
          aa1 = fmaf(tka, blo(v.y), aa1);  bb1 = fmaf(tkb, bhi(v.y), bb1);
          aa2 = fmaf(tka, blo(v.z), aa2);  bb2 = fmaf(tkb, bhi(v.z), bb2);
          aa3 = fmaf(tka, blo(v.w), aa3);  bb3 = fmaf(tkb, bhi(v.w), bb3);
        }
        uint4 o;
        o.x = pack2(aa0, bb0);
        o.y = pack2(aa1, bb1);
        o.z = pack2(aa2, bb2);
        o.w = pack2(aa3, bb3);
        *(uint4*)(zp + q * 4) = o;
      }
    }
    __syncthreads();
  }
}

// ---------------------------------------------------------------------------
// K2/K3 shared pieces: 128 pos x 128 out tile, 4 waves (wave = group),
// 4 tiles per block, double-buffered LDS staging (global->reg->LDS).
// ---------------------------------------------------------------------------
#define AFRAG_LOAD()                                                           \
  const int lr = tid & 15, lg = (tid >> 4) & 3, wv = tid >> 6;                 \
  const int obase = wv * 32;                                                   \
  short8v afrag[2][2];                                                         \
  _Pragma("unroll")                                                            \
  for (int ot = 0; ot < 2; ++ot)                                               \
    _Pragma("unroll")                                                          \
    for (int kt = 0; kt < 2; ++kt) {                                           \
      int o  = obase + ot * 16 + lr;                                           \
      int c0 = kt * 32 + lg * 8;                                               \
      float4 wa = *(const float4*)(pw + o * 64 + c0);                          \
      float4 wb = *(const float4*)(pw + o * 64 + c0 + 4);                      \
      short8v fr;                                                              \
      fr[0] = (short)f2bf(wa.x); fr[1] = (short)f2bf(wa.y);                    \
      fr[2] = (short)f2bf(wa.z); fr[3] = (short)f2bf(wa.w);                    \
      fr[4] = (short)f2bf(wb.x); fr[5] = (short)f2bf(wb.y);                    \
      fr[6] = (short)f2bf(wb.z); fr[7] = (short)f2bf(wb.w);                    \
      afrag[ot][kt] = fr;                                                      \
    }

#define LDR(it) {                                                              \
  int p0 = (it) * 128;                                                         \
  _Pragma("unroll")                                                            \
  for (int i = 0; i < 4; ++i) {                                                \
    int f = tid + i * 256; int c2r = f >> 5; int po = (f & 31) << 2;           \
    st[i] = *(const uint4*)(zb + (size_t)c2r * THW + p0 + po);                 \
  } }

#define STL(bf) {                                                              \
  _Pragma("unroll")                                                            \
  for (int i = 0; i < 4; ++i) {                                                \
    int f = tid + i * 256; int c2r = f >> 5; int po = (f & 31) << 2;           \
    *(uint4*)&zt[bf][c2r * 132 + po] = st[i];                                  \
  } }

#define MFMA_TILE(bufidx)                                                      \
  f32x4 acc[2][8];                                                             \
  _Pragma("unroll")                                                            \
  for (int ot = 0; ot < 2; ++ot)                                               \
    _Pragma("unroll")                                                          \
    for (int pt = 0; pt < 8; ++pt) {                                           \
      acc[ot][pt][0] = 0.f; acc[ot][pt][1] = 0.f;                              \
      acc[ot][pt][2] = 0.f; acc[ot][pt][3] = 0.f;                              \
    }                                                                          \
  {                                                                            \
    const unsigned int* ztc = zt[bufidx];                                      \
    _Pragma("unroll")                                                          \
    for (int kt = 0; kt < 2; ++kt) {                                           \
      const int c2b = kt * 16 + lg * 4;                                        \
      _Pragma("unroll")                                                        \
      for (int pt = 0; pt < 8; ++pt) {                                         \
        const unsigned int* zp2 = &ztc[c2b * 132 + pt * 16 + lr];              \
        union { unsigned int u[4]; short8v s; } bfu;                           \
        bfu.u[0] = zp2[0];   bfu.u[1] = zp2[132];                              \
        bfu.u[2] = zp2[264]; bfu.u[3] = zp2[396];                              \
        acc[0][pt] = __builtin_amdgcn_mfma_f32_16x16x32_bf16(                  \
            afrag[0][kt], bfu.s, acc[0][pt], 0, 0, 0);                         \
        acc[1][pt] = __builtin_amdgcn_mfma_f32_16x16x32_bf16(                  \
            afrag[1][kt], bfu.s, acc[1][pt], 0, 0, 0);                         \
      }                                                                        \
    }                                                                          \
  }

// K2: GEMM over 4 tiles -> per-(b,group) sum / sumsq (double atomics).
__global__ __launch_bounds__(256) void k2_stats(
    const unsigned int* __restrict__ zq, const float* __restrict__ pw,
    const float* __restrict__ pb, double* __restrict__ stats)
{
  __shared__ unsigned int zt[2][32 * 132];   // 33.8 KB
  const int tid = threadIdx.x;
  const int b  = blockIdx.x / 98;
  const int pg = blockIdx.x - b * 98;

  AFRAG_LOAD();

  float pbv[2][4];
#pragma unroll
  for (int ot = 0; ot < 2; ++ot)
#pragma unroll
    for (int r = 0; r < 4; ++r)
      pbv[ot][r] = pb[obase + ot * 16 + lg * 4 + r];

  const unsigned int* zb = zq + (size_t)(b * 32) * THW + pg * 512;

  uint4 st[4];
  LDR(0); STL(0);

  float s1 = 0.0f, s2 = 0.0f;
  for (int it = 0; it < 4; ++it) {
    __syncthreads();
    if (it < 3) LDR(it + 1);
    MFMA_TILE(it & 1);
    if (it < 3) STL((it + 1) & 1);
#pragma unroll
    for (int ot = 0; ot < 2; ++ot)
#pragma unroll
      for (int pt = 0; pt < 8; ++pt)
#pragma unroll
        for (int r = 0; r < 4; ++r) {
          float d = acc[ot][pt][r] + pbv[ot][r];
          s1 += d;
          s2 = fmaf(d, d, s2);
        }
  }

#pragma unroll
  for (int off = 32; off; off >>= 1) {
    s1 += __shfl_xor(s1, off);
    s2 += __shfl_xor(s2, off);
  }
  if ((tid & 63) == 0) {
    atomicAdd(&stats[(b * 4 + wv) * 2 + 0], (double)s1);
    atomicAdd(&stats[(b * 4 + wv) * 2 + 1], (double)s2);
  }
}

// K3: GEMM recompute over 4 tiles -> GroupNorm + affine + ReLU -> out.
__global__ __launch_bounds__(256) void k3_norm(
    const unsigned int* __restrict__ zq, const float* __restrict__ pw,
    const float* __restrict__ pb, const double* __restrict__ stats,
    const float* __restrict__ gnw, const float* __restrict__ gnb,
    float* __restrict__ out)
{
  __shared__ unsigned int zt[2][32 * 132];
  const int tid = threadIdx.x;
  const int b  = blockIdx.x / 98;
  const int pg = blockIdx.x - b * 98;

  AFRAG_LOAD();

  double sm1 = stats[(b * 4 + wv) * 2 + 0];
  double sm2 = stats[(b * 4 + wv) * 2 + 1];
  double md = sm1 / NPG;
  double vd = sm2 / NPG - md * md;
  float m   = (float)md;
  float inv = rsqrtf((float)vd + 1e-5f);

  float Ac[2][4], Bc[2][4];
#pragma unroll
  for (int ot = 0; ot < 2; ++ot)
#pragma unroll
    for (int r = 0; r < 4; ++r) {
      int o = obase + ot * 16 + lg * 4 + r;
      float A = inv * gnw[o];
      Ac[ot][r] = A;
      Bc[ot][r] = fmaf(pb[o] - m, A, gnb[o]);
    }

  const unsigned int* zb = zq + (size_t)(b * 32) * THW + pg * 512;
  float* ob = out + (size_t)(b * COUT) * THW + pg * 512 + lr;

  uint4 st[4];
  LDR(0); STL(0);

  for (int it = 0; it < 4; ++it) {
    __syncthreads();
    if (it < 3) LDR(it + 1);
    MFMA_TILE(it & 1);
    if (it < 3) STL((it + 1) & 1);
#pragma unroll
    for (int ot = 0; ot < 2; ++ot)
#pragma unroll
      for (int r = 0; r < 4; ++r) {
        int o = obase + ot * 16 + lg * 4 + r;
        float* orow = ob + (size_t)o * THW + it * 128;
        float A = Ac[ot][r], B = Bc[ot][r];
#pragma unroll
        for (int pt = 0; pt < 8; ++pt) {
          float v = fmaf(acc[ot][pt][r], A, B);
          orow[pt * 16] = v > 0.0f ? v : 0.0f;
        }
      }
  }
}

// ---------------------------------------------------------------------------
extern "C" void kernel_launch(void* const* d_in, const int* in_sizes, int n_in,
                              void* d_out, int out_size, void* d_ws, size_t ws_size,
                              hipStream_t stream)
{
  const float* x   = (const float*)d_in[0];
  const float* sw  = (const float*)d_in[1];
  const float* sb  = (const float*)d_in[2];
  const float* tw  = (const float*)d_in[3];
  const float* tb  = (const float*)d_in[4];
  const float* pw  = (const float*)d_in[5];
  const float* pb  = (const float*)d_in[6];
  const float* gnw = (const float*)d_in[7];
  const float* gnb = (const float*)d_in[8];
  float* out = (float*)d_out;

  double* stats    = (double*)d_ws;                        // 64 doubles
  unsigned int* zq = (unsigned int*)((char*)d_ws + 512);   // bf16-pair z

  hipMemsetAsync(stats, 0, 64 * sizeof(double), stream);

  k1_dwconv<<<Bb * 32 * 4, 256, 0, stream>>>(x, sw, sb, tw, tb, zq);  // 1024
  k2_stats<<<Bb * 98, 256, 0, stream>>>(zq, pw, pb, stats);           // 784
  k3_norm <<<Bb * 98, 256, 0, stream>>>(zq, pw, pb, stats, gnw, gnb, out);
}